// Round 18
// baseline (870.358 us; speedup 1.0000x reference)
//
#include <hip/hip_runtime.h>
#include <hip/hip_bf16.h>
#include <math.h>

// dims
#define MMX 64
#define NNX 128
#define DDX 64
#define RDX 128
#define TTX 96
#define LLX 512
#define PROWS 67    // padded rows: m in [-1, 65]
#define PCOLS 130   // padded cols: n in [-1, 128]

typedef short bfx8 __attribute__((ext_vector_type(8)));
typedef float floatx4 __attribute__((ext_vector_type(4)));

__device__ __forceinline__ float gelu(float v) {
  return 0.5f * v * (1.0f + erff(v * 0.70710678118654752f));
}

// async global->LDS DMA, 16B per lane (dest = wave-uniform base + lane*16)
__device__ __forceinline__ void gload_lds16(const void* g, void* l) {
  __builtin_amdgcn_global_load_lds(
      (const __attribute__((address_space(1))) unsigned int*)g,
      (__attribute__((address_space(3))) unsigned int*)l, 16, 0, 0);
}

// ---------------------------------------------------------------------------
// prep: conv weight fp32 [CO][CI][4][3] -> bf16 [dd=dm*3+dn][co][ci]
// ---------------------------------------------------------------------------
__global__ __launch_bounds__(256) void castw_kernel(
    const float* __restrict__ w, __hip_bfloat16* __restrict__ o, int CO, int CI) {
  int i = blockIdx.x * 256 + threadIdx.x;      // CO*CI*12 total
  int ci = i % CI;
  int t = i / CI;
  int co = t % CO;
  int dd = t / CO;
  o[i] = __float2bfloat16(w[(size_t)(co * CI + ci) * 12 + dd]);
}

// ---------------------------------------------------------------------------
// prep: head weight fp32 [96][f=d*128+n] -> bf16 [96][fh=n*64+d]
// ---------------------------------------------------------------------------
__global__ __launch_bounds__(256) void headw_kernel(
    const float* __restrict__ hw, __hip_bfloat16* __restrict__ o) {
  int i = blockIdx.x * 256 + threadIdx.x;      // 96*8192 total
  int fh = i & 8191;
  int t = i >> 13;
  int d = fh & 63;
  int n = fh >> 6;
  o[i] = __float2bfloat16(hw[(size_t)t * 8192 + d * 128 + n]);
}

// ---------------------------------------------------------------------------
// embed: x [B*M, L] fp32 -> X [Bc*M, N, D] fp32 (k=8 stride=4, edge-pad right)
// ---------------------------------------------------------------------------
__global__ __launch_bounds__(256) void embed_kernel(
    const float* __restrict__ x, const float* __restrict__ w,
    const float* __restrict__ bias, float* __restrict__ xe, int bm_off) {
  int tid = blockIdx.x * 256 + threadIdx.x;
  int d  = tid & 63;
  int n  = (tid >> 6) & 127;
  int bm = tid >> 13;
  const float* xr = x + (size_t)(bm_off + bm) * LLX;
  float acc = bias[d];
  int base = n * 4;
#pragma unroll
  for (int p = 0; p < 8; ++p) {
    int i = base + p;
    if (i > LLX - 1) i = LLX - 1;
    acc += w[d * 8 + p] * xr[i];
  }
  xe[tid] = acc;
}

// ---------------------------------------------------------------------------
// depthwise conv over M (k=4, zero-pad 1/2): X fp32 [b,m,n,d] -> Yp bf16 padded
// Rolling register window over m: X read ONCE.
// Yp layout [b][PROWS][PCOLS][64], interior at [m+1][n+1]; halos pre-zeroed.
// ---------------------------------------------------------------------------
__global__ __launch_bounds__(256) void dw_kernel(
    const float* __restrict__ xe, const float* __restrict__ w,
    const float* __restrict__ bias, __hip_bfloat16* __restrict__ yp) {
  const int tid = threadIdx.x;
  const int d = tid & 63;
  const int n = ((blockIdx.x & 31) << 2) + (tid >> 6);
  const int b = blockIdx.x >> 5;
  const int c = n * DDX + d;
  const float w0 = w[c * 4 + 0], w1 = w[c * 4 + 1];
  const float w2 = w[c * 4 + 2], w3 = w[c * 4 + 3];
  const float bv = bias[c];
  const float* src = xe + ((size_t)b * MMX * NNX + n) * DDX + d;
  __hip_bfloat16* dst = yp + (((size_t)b * PROWS + 1) * PCOLS + n + 1) * DDX + d;
  const int sstr = NNX * DDX;
  const int dstr = PCOLS * DDX;
  // taps: out[m] = w0*x[m-1] + w1*x[m] + w2*x[m+1] + w3*x[m+2], zero-pad
  float xm1 = 0.f, x0 = src[0], xp1 = src[sstr], xp2;
#pragma unroll 4
  for (int m = 0; m < MMX; ++m) {
    xp2 = (m + 2 < MMX) ? src[(size_t)(m + 2) * sstr] : 0.f;
    float acc = bv + w0 * xm1 + w1 * x0 + w2 * xp1 + w3 * xp2;
    dst[(size_t)m * dstr] = __float2bfloat16(acc);
    xm1 = x0; x0 = xp1; xp1 = xp2;
  }
}

// ---------------------------------------------------------------------------
// MFMA conv2d 4x3. Block = one (b,m). r18: 512 threads / 8 WAVES.
// r17 counters (spill fixed: WRITE 364->98MB exactly as predicted): conv2
// 129us with MfmaUtil 16%, VALU 9%, HBM 20%, Occ 41% -- pure LATENCY bound.
// Per-wave serial span = 48 phases x ~300cyc Bf-load latency; 4 lockstep
// waves/block can't cover it, and the allocator's immovable 64-VGPR budget
// (r10/r13/r15/r17) forbids register prefetch. FIX: match the structure to
// the budget -- 8 waves/block, smaller per-wave tiles (fit 64 VGPR), 2x the
// independent streams per SIMD (up to 32 waves/CU at 4 blocks/CU by LDS):
//   conv1 (64->128): WPX=2,WCO=4 -> wave 64px x 32co (PT=4,CT=2, acc 32)
//   conv2 (128->64): WPX=4,WCO=2 -> wave 32px x 32co (PT=2,CT=2, acc 16)
// KEPT (r16): zero-VGPR DMA staging (global_load_lds w16), linear LDS +
// both-sides XOR swizzle (src chunk c^(r&(NS-1)), same XOR on read slot).
// KEPT (r4): fully-unrolled epilogue (compile-time acc indices).
// KEPT: Bf per-(dn,kc) (CT bfx8 live); single-a reads; XCD swizzle.
// in padded [b][67][130][CIN]; wT [12][COUT][CIN].
// GELU: write Hp padded interior (bf16). else: X += resid (fp32) and Xb bf16.
// ---------------------------------------------------------------------------
template <int CIN, int COUT, bool GELU, int WPX>
__global__ __launch_bounds__(512) void conv_lds(
    const __hip_bfloat16* __restrict__ in,
    const __hip_bfloat16* __restrict__ wT,
    const float* __restrict__ bias,
    __hip_bfloat16* __restrict__ hout,   // padded [b][67][130][COUT]
    float* xio,                          // [b][64][128][COUT] fp32
    __hip_bfloat16* __restrict__ xb) {   // [b][64][128][COUT] bf16
  constexpr int WAVES = 8;
  constexpr int KC = CIN / 32;           // k-chunks per (dm,dn)
  constexpr int WCO = WAVES / WPX;       // waves along co
  constexpr int PT = 8 / WPX;            // 16-px tiles per wave
  constexpr int CT = COUT / 16 / WCO;    // 16-co tiles per wave (=2 both convs)
  constexpr int NS = CIN / 8;            // 16B chunks per row
  constexpr int TOTCH = 130 * NS;        // 16B chunks per padded row-line
  constexpr int PER = (TOTCH + 511) / 512;  // 3 (conv1) / 5 (conv2)
  // smem: linear A-tile [130][CIN] shorts; epilogue scratch may be larger
  constexpr int EPI = GELU ? 64 * (COUT + 8) : 64 * (COUT + 4) * 2;  // shorts
  constexpr int SMEMN = (130 * CIN > EPI) ? 130 * CIN : EPI;
  __shared__ short smem[SMEMN];          // conv1 17.4 KB, conv2 33.3 KB

  // bijective XCD swizzle (grid = Bc*64, always %8==0)
  const int nwg = gridDim.x;
  const int wid = (blockIdx.x & 7) * (nwg >> 3) + (blockIdx.x >> 3);
  const int m = wid & 63;
  const int b = wid >> 6;
  const int tid = threadIdx.x;
  const int lane = tid & 63;
  const int w = tid >> 6;               // 0..7
  const int wco = w % WCO;
  const int wpx = w / WCO;
  const int wc0 = wco * (16 * CT);
  const int px0 = wpx * (16 * PT);
  const int l15 = lane & 15;
  const int quad = lane >> 4;

  floatx4 acc[PT][CT];
#pragma unroll
  for (int i = 0; i < PT; ++i)
#pragma unroll
    for (int j = 0; j < CT; ++j) acc[i][j] = (floatx4)0.f;

  const __hip_bfloat16* inrow = in + ((size_t)b * PROWS + m) * PCOLS * CIN;

#pragma unroll 1
  for (int dm = 0; dm < 4; ++dm) {
    __syncthreads();  // (A) prior K-step smem reads done before DMA overwrite
    // DMA row (m+dm) -> smem linear, XOR-swizzled SOURCE (zero VGPR held)
    {
      const __hip_bfloat16* rowp = inrow + (size_t)dm * PCOLS * CIN;
#pragma unroll
      for (int p = 0; p < PER; ++p) {
        int s = tid + p * 512;
        if (s < TOTCH) {
          int r = s / NS, c = s % NS;
          int cs = c ^ (r & (NS - 1));
          gload_lds16(rowp + (size_t)r * CIN + cs * 8, smem + s * 8);
        }
      }
    }
    __syncthreads();  // (B) drains vmcnt -> staged row visible

    const __hip_bfloat16* wbase = wT + (size_t)dm * 3 * COUT * CIN;
#pragma unroll
    for (int dn = 0; dn < 3; ++dn) {
#pragma unroll
      for (int kc = 0; kc < KC; ++kc) {
        // B fragments for THIS (dn,kc) only (live range: CT=2 bfx8)
        bfx8 Bf[CT];
#pragma unroll
        for (int j = 0; j < CT; ++j)
          Bf[j] = *(const bfx8*)(
              wbase + ((size_t)dn * COUT + wc0 + 16 * j + l15) * CIN +
              kc * 32 + quad * 8);
#pragma unroll
        for (int i = 0; i < PT; ++i) {
          // A fragment: row-major linear + XOR-swizzled slot (matches DMA)
          const int rowa = px0 + 16 * i + l15 + dn;
          const int slot = kc * 4 + quad;
          bfx8 a = *(const bfx8*)&smem[rowa * CIN +
                                       ((slot ^ (rowa & (NS - 1))) << 3)];
#pragma unroll
          for (int j = 0; j < CT; ++j)
            acc[i][j] = __builtin_amdgcn_mfma_f32_16x16x32_bf16(
                a, Bf[j], acc[i][j], 0, 0, 0);
        }
      }
    }
  }

  // bias
  float bs[CT];
#pragma unroll
  for (int j = 0; j < CT; ++j) bs[j] = bias[wc0 + 16 * j + l15];

  // epilogue: LDS transpose per 64-px half -> coalesced wide stores.
  // FULLY UNROLLED over h (compile-time acc indices -- no scratch demotion).
  // Unified tile mapping: wave owns global 16-px tiles g = wpx*PT + i;
  // tile g belongs to half h iff g>>2 == h; row-in-half ii = g&3.
  __syncthreads();  // all K-loop smem reads done before reuse
#pragma unroll
  for (int h = 0; h < 2; ++h) {
    if (GELU) {
      constexpr int STR2 = COUT + 8;     // shorts
      short* t2 = smem;
#pragma unroll
      for (int i = 0; i < PT; ++i) {
        int g = wpx * PT + i;
        if ((g >> 2) == h) {
          int ii = g & 3;
#pragma unroll
          for (int j = 0; j < CT; ++j)
#pragma unroll
            for (int r = 0; r < 4; ++r) {
              int pl = 16 * ii + quad * 4 + r;
              __hip_bfloat16 bv = __float2bfloat16(gelu(acc[i][j][r] + bs[j]));
              t2[pl * STR2 + wc0 + 16 * j + l15] = *(short*)&bv;
            }
        }
      }
      __syncthreads();
      constexpr int CHUNKS = 64 * COUT / 8;   // 1024
      size_t gbase = (((size_t)b * PROWS + m + 1) * PCOLS + 1 + h * 64) * COUT;
      for (int idx = tid; idx < CHUNKS; idx += 512) {
        int px = idx / (COUT / 8), cg = idx % (COUT / 8);
        uint4 v = *(uint4*)&t2[px * STR2 + cg * 8];
        *(uint4*)(hout + gbase + (size_t)px * COUT + cg * 8) = v;
      }
      __syncthreads();
    } else {
      constexpr int STRF = COUT + 4;     // floats
      float* tf = (float*)smem;
#pragma unroll
      for (int i = 0; i < PT; ++i) {
        int g = wpx * PT + i;
        if ((g >> 2) == h) {
          int ii = g & 3;
#pragma unroll
          for (int j = 0; j < CT; ++j)
#pragma unroll
            for (int r = 0; r < 4; ++r) {
              int pl = 16 * ii + quad * 4 + r;
              tf[pl * STRF + wc0 + 16 * j + l15] = acc[i][j][r] + bs[j];
            }
        }
      }
      __syncthreads();
      constexpr int CHUNKS = 64 * COUT / 4;   // 1024
      size_t gbase = (((size_t)b * MMX + m) * NNX + h * 64) * COUT;
      for (int idx = tid; idx < CHUNKS; idx += 512) {
        int px = idx / (COUT / 4), cg = idx % (COUT / 4);
        float4 a4 = *(float4*)&tf[px * STRF + cg * 4];
        size_t gx = gbase + (size_t)px * COUT + cg * 4;
        float4 xv = *(float4*)(xio + gx);
        float4 rr = make_float4(a4.x + xv.x, a4.y + xv.y, a4.z + xv.z, a4.w + xv.w);
        *(float4*)(xio + gx) = rr;
        __hip_bfloat16 o0 = __float2bfloat16(rr.x), o1 = __float2bfloat16(rr.y);
        __hip_bfloat16 o2 = __float2bfloat16(rr.z), o3 = __float2bfloat16(rr.w);
        ushort4 ov = make_ushort4(*(unsigned short*)&o0, *(unsigned short*)&o1,
                                  *(unsigned short*)&o2, *(unsigned short*)&o3);
        *(ushort4*)(xb + gx) = ov;
      }
      __syncthreads();
    }
  }
}

// ---------------------------------------------------------------------------
// head split-K: P[ks][bm][t] = sum_{k in slice} Xb[bm][k] * hwT[t][k]
// grid = Bc * 8; block = 64 bm x 96 t x K=1024. 4 waves = 16 bm each.
// ---------------------------------------------------------------------------
__global__ __launch_bounds__(256) void head_split(
    const __hip_bfloat16* __restrict__ xb,   // [nbm][8192]
    const __hip_bfloat16* __restrict__ hwT,  // [96][8192]
    float* __restrict__ P, int nbm) {        // [8][nbm][96]
  const int ks = blockIdx.x & 7;
  const int bm0 = (blockIdx.x >> 3) * 64;
  const int lane = threadIdx.x & 63;
  const int w = threadIdx.x >> 6;
  const int l15 = lane & 15;
  const int quad = lane >> 4;
  const int bmw = bm0 + w * 16;

  floatx4 acc[6];
#pragma unroll
  for (int j = 0; j < 6; ++j) acc[j] = (floatx4)0.f;

  const int k0 = ks * 1024;
  const __hip_bfloat16* abase = xb + (size_t)(bmw + l15) * 8192 + k0;
  const __hip_bfloat16* bbase = hwT + (size_t)l15 * 8192 + k0;
#pragma unroll 4
  for (int kc = 0; kc < 32; ++kc) {
    const int kb = kc * 32 + quad * 8;
    bfx8 a = *(const bfx8*)(abase + kb);
#pragma unroll
    for (int j = 0; j < 6; ++j) {
      bfx8 bv = *(const bfx8*)(bbase + (size_t)(16 * j) * 8192 + kb);
      acc[j] = __builtin_amdgcn_mfma_f32_16x16x32_bf16(a, bv, acc[j], 0, 0, 0);
    }
  }
#pragma unroll
  for (int j = 0; j < 6; ++j) {
    int t = 16 * j + l15;
#pragma unroll
    for (int r = 0; r < 4; ++r) {
      int bm = bmw + quad * 4 + r;
      P[((size_t)ks * nbm + bm) * TTX + t] = acc[j][r];
    }
  }
}

__global__ __launch_bounds__(256) void head_reduce(
    const float* __restrict__ P, const float* __restrict__ hb,
    float* __restrict__ out, int nbm, int bm_off) {
  int i = blockIdx.x * 256 + threadIdx.x;    // nbm*96
  int t = i % TTX;
  int bm = i / TTX;
  float s = hb[t];
#pragma unroll
  for (int ks = 0; ks < 8; ++ks) s += P[((size_t)ks * nbm + bm) * TTX + t];
  out[(size_t)(bm_off + bm) * TTX + t] = s;
}

// ---------------------------------------------------------------------------
extern "C" void kernel_launch(void* const* d_in, const int* in_sizes, int n_in,
                              void* d_out, int out_size, void* d_ws, size_t ws_size,
                              hipStream_t stream) {
  const float* x      = (const float*)d_in[0];
  const float* emb_w  = (const float*)d_in[1];
  const float* emb_b  = (const float*)d_in[2];
  const float* head_w = (const float*)d_in[3];
  const float* head_b = (const float*)d_in[4];
  const float* dw_w1  = (const float*)d_in[5];
  const float* dw_b1  = (const float*)d_in[6];
  const float* f11_w  = (const float*)d_in[7];
  const float* f11_b  = (const float*)d_in[8];
  const float* f12_w  = (const float*)d_in[9];
  const float* f12_b  = (const float*)d_in[10];
  const float* dw_w2  = (const float*)d_in[11];
  const float* dw_b2  = (const float*)d_in[12];
  const float* f21_w  = (const float*)d_in[13];
  const float* f21_b  = (const float*)d_in[14];
  const float* f22_w  = (const float*)d_in[15];
  const float* f22_b  = (const float*)d_in[16];

  // fixed: 4 conv wT (98304 bf16 each) + hwT (786432 bf16)
  const size_t WEL = 98304, HWEL = 786432;
  __hip_bfloat16* wt11 = (__hip_bfloat16*)d_ws;
  __hip_bfloat16* wt12 = wt11 + WEL;
  __hip_bfloat16* wt21 = wt12 + WEL;
  __hip_bfloat16* wt22 = wt21 + WEL;
  __hip_bfloat16* hwT  = wt22 + WEL;
  char* dyn = (char*)(hwT + HWEL);
  const size_t fixed_bytes = (4 * WEL + HWEL) * 2;

  const size_t YP_B = (size_t)PROWS * PCOLS * DDX * 2;    // 1,114,880
  const size_t HP_B = (size_t)PROWS * PCOLS * RDX * 2;    // 2,229,760
  const size_t X_B  = (size_t)MMX * NNX * DDX * 4;        // 2,097,152
  const size_t XB_B = (size_t)MMX * NNX * DDX * 2;        // 1,048,576
  const size_t P_B  = (size_t)8 * MMX * TTX * 4;          //   196,608
  const size_t PER_B = YP_B + HP_B + X_B + XB_B + P_B;
  int Bc = 32;
  while (Bc > 1 && fixed_bytes + (size_t)Bc * PER_B > ws_size) Bc >>= 1;

  __hip_bfloat16* Yp = (__hip_bfloat16*)dyn;
  __hip_bfloat16* Hp = (__hip_bfloat16*)(dyn + (size_t)Bc * YP_B);
  float* X  = (float*)(dyn + (size_t)Bc * (YP_B + HP_B));
  __hip_bfloat16* Xb = (__hip_bfloat16*)(dyn + (size_t)Bc * (YP_B + HP_B + X_B));
  float* P  = (float*)(dyn + (size_t)Bc * (YP_B + HP_B + X_B + XB_B));
  const int nbm = Bc * MMX;

  // prep (once per launch)
  castw_kernel<<<384, 256, 0, stream>>>(f11_w, wt11, RDX, DDX);
  castw_kernel<<<384, 256, 0, stream>>>(f12_w, wt12, DDX, RDX);
  castw_kernel<<<384, 256, 0, stream>>>(f21_w, wt21, RDX, DDX);
  castw_kernel<<<384, 256, 0, stream>>>(f22_w, wt22, DDX, RDX);
  headw_kernel<<<3072, 256, 0, stream>>>(head_w, hwT);
  // zero padded halo buffers (ws is re-poisoned before every timed launch)
  hipMemsetAsync(Yp, 0, (size_t)Bc * (YP_B + HP_B), stream);

  for (int b0 = 0; b0 < 32; b0 += Bc) {
    int bm_off = b0 * MMX;
    embed_kernel<<<Bc * 2048, 256, 0, stream>>>(x, emb_w, emb_b, X, bm_off);

    for (int l = 0; l < 2; ++l) {
      const float* dwW = l ? dw_w2 : dw_w1;
      const float* dwB = l ? dw_b2 : dw_b1;
      const __hip_bfloat16* w1 = l ? wt21 : wt11;
      const float* b1 = l ? f21_b : f11_b;
      const __hip_bfloat16* w2 = l ? wt22 : wt12;
      const float* b2 = l ? f22_b : f12_b;

      dw_kernel<<<Bc * 32, 256, 0, stream>>>(X, dwW, dwB, Yp);
      conv_lds<DDX, RDX, true, 2>
          <<<Bc * MMX, 512, 0, stream>>>(Yp, w1, b1, Hp, nullptr, nullptr);
      conv_lds<RDX, DDX, false, 4>
          <<<Bc * MMX, 512, 0, stream>>>(Hp, w2, b2, nullptr, X, Xb);
    }

    head_split<<<Bc * 8, 256, 0, stream>>>(Xb, hwT, P, nbm);
    head_reduce<<<Bc * 24, 256, 0, stream>>>(P, head_b, (float*)d_out, nbm, bm_off);
  }
}

// Round 19
// 629.802 us; speedup vs baseline: 1.3820x; 1.3820x over previous
//
#include <hip/hip_runtime.h>
#include <hip/hip_bf16.h>
#include <math.h>

// dims
#define MMX 64
#define NNX 128
#define DDX 64
#define RDX 128
#define TTX 96
#define LLX 512
#define PROWS 67    // padded rows: m in [-1, 65]
#define PCOLS 130   // padded cols: n in [-1, 128]

typedef short bfx8 __attribute__((ext_vector_type(8)));
typedef float floatx4 __attribute__((ext_vector_type(4)));

__device__ __forceinline__ float gelu(float v) {
  return 0.5f * v * (1.0f + erff(v * 0.70710678118654752f));
}

// async global->LDS DMA, 16B per lane (dest = wave-uniform base + lane*16)
__device__ __forceinline__ void gload_lds16(const void* g, void* l) {
  __builtin_amdgcn_global_load_lds(
      (const __attribute__((address_space(1))) unsigned int*)g,
      (__attribute__((address_space(3))) unsigned int*)l, 16, 0, 0);
}

// ---------------------------------------------------------------------------
// prep: conv weight fp32 [CO][CI][4][3] -> bf16 [dd=dm*3+dn][co][ci]
// ---------------------------------------------------------------------------
__global__ __launch_bounds__(256) void castw_kernel(
    const float* __restrict__ w, __hip_bfloat16* __restrict__ o, int CO, int CI) {
  int i = blockIdx.x * 256 + threadIdx.x;      // CO*CI*12 total
  int ci = i % CI;
  int t = i / CI;
  int co = t % CO;
  int dd = t / CO;
  o[i] = __float2bfloat16(w[(size_t)(co * CI + ci) * 12 + dd]);
}

// ---------------------------------------------------------------------------
// prep: head weight fp32 [96][f=d*128+n] -> bf16 [96][fh=n*64+d]
// ---------------------------------------------------------------------------
__global__ __launch_bounds__(256) void headw_kernel(
    const float* __restrict__ hw, __hip_bfloat16* __restrict__ o) {
  int i = blockIdx.x * 256 + threadIdx.x;      // 96*8192 total
  int fh = i & 8191;
  int t = i >> 13;
  int d = fh & 63;
  int n = fh >> 6;
  o[i] = __float2bfloat16(hw[(size_t)t * 8192 + d * 128 + n]);
}

// ---------------------------------------------------------------------------
// embed: x [B*M, L] fp32 -> X [Bc*M, N, D] fp32 (k=8 stride=4, edge-pad right)
// ---------------------------------------------------------------------------
__global__ __launch_bounds__(256) void embed_kernel(
    const float* __restrict__ x, const float* __restrict__ w,
    const float* __restrict__ bias, float* __restrict__ xe, int bm_off) {
  int tid = blockIdx.x * 256 + threadIdx.x;
  int d  = tid & 63;
  int n  = (tid >> 6) & 127;
  int bm = tid >> 13;
  const float* xr = x + (size_t)(bm_off + bm) * LLX;
  float acc = bias[d];
  int base = n * 4;
#pragma unroll
  for (int p = 0; p < 8; ++p) {
    int i = base + p;
    if (i > LLX - 1) i = LLX - 1;
    acc += w[d * 8 + p] * xr[i];
  }
  xe[tid] = acc;
}

// ---------------------------------------------------------------------------
// depthwise conv over M (k=4, zero-pad 1/2): X fp32 [b,m,n,d] -> Yp bf16 padded
// Rolling register window over m: X read ONCE.
// Yp layout [b][PROWS][PCOLS][64], interior at [m+1][n+1]; halos pre-zeroed.
// ---------------------------------------------------------------------------
__global__ __launch_bounds__(256) void dw_kernel(
    const float* __restrict__ xe, const float* __restrict__ w,
    const float* __restrict__ bias, __hip_bfloat16* __restrict__ yp) {
  const int tid = threadIdx.x;
  const int d = tid & 63;
  const int n = ((blockIdx.x & 31) << 2) + (tid >> 6);
  const int b = blockIdx.x >> 5;
  const int c = n * DDX + d;
  const float w0 = w[c * 4 + 0], w1 = w[c * 4 + 1];
  const float w2 = w[c * 4 + 2], w3 = w[c * 4 + 3];
  const float bv = bias[c];
  const float* src = xe + ((size_t)b * MMX * NNX + n) * DDX + d;
  __hip_bfloat16* dst = yp + (((size_t)b * PROWS + 1) * PCOLS + n + 1) * DDX + d;
  const int sstr = NNX * DDX;
  const int dstr = PCOLS * DDX;
  // taps: out[m] = w0*x[m-1] + w1*x[m] + w2*x[m+1] + w3*x[m+2], zero-pad
  float xm1 = 0.f, x0 = src[0], xp1 = src[sstr], xp2;
#pragma unroll 4
  for (int m = 0; m < MMX; ++m) {
    xp2 = (m + 2 < MMX) ? src[(size_t)(m + 2) * sstr] : 0.f;
    float acc = bv + w0 * xm1 + w1 * x0 + w2 * xp1 + w3 * xp2;
    dst[(size_t)m * dstr] = __float2bfloat16(acc);
    xm1 = x0; x0 = xp1; xp1 = xp2;
  }
}

// ---------------------------------------------------------------------------
// MFMA conv2d 4x3. Block = one (b,m). r19: REVERT to 256 thr / 4 waves
// (r18's 512-thr halved per-phase MFMA work while keeping per-phase load
// latency: MfmaUtil 9.8%, 211us -- worse). Benched-best shape (r17, 648us):
//   conv1 (64->128): WPX=1 -> wave = 128px x 32co (PT=8, CT=2)
//   conv2 (128->64): WPX=2 -> wave =  64px x 32co (PT=4, CT=2)
// r19 CHANGE: Bf hoisted PER-DN ([KC][CT] batch, one ~300cyc L2 exposure)
// instead of per-(dn,kc) -- latency events/block: conv2 48->12, conv1
// 24->12. Arch-VGPR demand excl. AGPR-resident acc: conv2 ~50, conv1 ~35
// (conv1's clean r17 run with acc=64 proves compiler puts acc in AGPRs).
// FALSIFICATION: WRITE_SIZE jumping above ~98MB = the hoist spilled.
// KEPT (r16): zero-VGPR DMA staging (global_load_lds w16), linear LDS +
// both-sides XOR swizzle (src chunk c^(r&(NS-1)), same XOR on read slot).
// KEPT (r4): fully-unrolled epilogue (compile-time acc indices).
// XCD-swizzled (b,m). in padded [b][67][130][CIN]; wT [12][COUT][CIN].
// GELU: write Hp padded interior (bf16). else: X += resid (fp32) and Xb bf16.
// ---------------------------------------------------------------------------
template <int CIN, int COUT, bool GELU, int WPX>
__global__ __launch_bounds__(256) void conv_lds(
    const __hip_bfloat16* __restrict__ in,
    const __hip_bfloat16* __restrict__ wT,
    const float* __restrict__ bias,
    __hip_bfloat16* __restrict__ hout,   // padded [b][67][130][COUT]
    float* xio,                          // [b][64][128][COUT] fp32
    __hip_bfloat16* __restrict__ xb) {   // [b][64][128][COUT] bf16
  constexpr int KC = CIN / 32;           // k-chunks per (dm,dn)
  constexpr int WCO = 4 / WPX;           // waves along co
  constexpr int PT = 8 / WPX;            // 16-px tiles per wave
  constexpr int CT = COUT / 16 / WCO;    // 16-co tiles per wave (=2 both convs)
  constexpr int NS = CIN / 8;            // 16B chunks per row
  constexpr int TOTCH = 130 * NS;        // 16B chunks per padded row-line
  constexpr int PER = (TOTCH + 255) / 256;  // 5 (conv1) / 9 (conv2)
  // smem: linear A-tile [130][CIN] shorts; epilogue scratch may be larger
  constexpr int EPI = GELU ? 64 * (COUT + 8) : 64 * (COUT + 4) * 2;  // shorts
  constexpr int SMEMN = (130 * CIN > EPI) ? 130 * CIN : EPI;
  __shared__ short smem[SMEMN];          // conv1 17.4 KB, conv2 33.3 KB

  // bijective XCD swizzle (grid = Bc*64, always %8==0)
  const int nwg = gridDim.x;
  const int wid = (blockIdx.x & 7) * (nwg >> 3) + (blockIdx.x >> 3);
  const int m = wid & 63;
  const int b = wid >> 6;
  const int tid = threadIdx.x;
  const int lane = tid & 63;
  const int w = tid >> 6;
  const int wco = w % WCO;
  const int wpx = w / WCO;
  const int wc0 = wco * (16 * CT);
  const int px0 = wpx * (16 * PT);
  const int l15 = lane & 15;
  const int quad = lane >> 4;

  floatx4 acc[PT][CT];
#pragma unroll
  for (int i = 0; i < PT; ++i)
#pragma unroll
    for (int j = 0; j < CT; ++j) acc[i][j] = (floatx4)0.f;

  const __hip_bfloat16* inrow = in + ((size_t)b * PROWS + m) * PCOLS * CIN;

#pragma unroll 1
  for (int dm = 0; dm < 4; ++dm) {
    __syncthreads();  // (A) prior K-step smem reads done before DMA overwrite
    // DMA row (m+dm) -> smem linear, XOR-swizzled SOURCE (zero VGPR held)
    {
      const __hip_bfloat16* rowp = inrow + (size_t)dm * PCOLS * CIN;
#pragma unroll
      for (int p = 0; p < PER; ++p) {
        int s = tid + p * 256;
        if (s < TOTCH) {
          int r = s / NS, c = s % NS;
          int cs = c ^ (r & (NS - 1));
          gload_lds16(rowp + (size_t)r * CIN + cs * 8, smem + s * 8);
        }
      }
    }
    __syncthreads();  // (B) drains vmcnt -> staged row visible

    const __hip_bfloat16* wbase = wT + (size_t)dm * 3 * COUT * CIN;
#pragma unroll
    for (int dn = 0; dn < 3; ++dn) {
      // Bf batch for the WHOLE dn (KC*CT independent loads -> ONE latency
      // exposure). conv2: 8 bfx8 = 32 VGPR; conv1: 4 bfx8 = 16 VGPR.
      bfx8 Bf[KC][CT];
#pragma unroll
      for (int kc = 0; kc < KC; ++kc)
#pragma unroll
        for (int j = 0; j < CT; ++j)
          Bf[kc][j] = *(const bfx8*)(
              wbase + ((size_t)dn * COUT + wc0 + 16 * j + l15) * CIN +
              kc * 32 + quad * 8);
#pragma unroll
      for (int kc = 0; kc < KC; ++kc) {
#pragma unroll
        for (int i = 0; i < PT; ++i) {
          // A fragment: row-major linear + XOR-swizzled slot (matches DMA)
          const int rowa = px0 + 16 * i + l15 + dn;
          const int slot = kc * 4 + quad;
          bfx8 a = *(const bfx8*)&smem[rowa * CIN +
                                       ((slot ^ (rowa & (NS - 1))) << 3)];
#pragma unroll
          for (int j = 0; j < CT; ++j)
            acc[i][j] = __builtin_amdgcn_mfma_f32_16x16x32_bf16(
                a, Bf[kc][j], acc[i][j], 0, 0, 0);
        }
      }
    }
  }

  // bias
  float bs[CT];
#pragma unroll
  for (int j = 0; j < CT; ++j) bs[j] = bias[wc0 + 16 * j + l15];

  // epilogue: LDS transpose per 64-px half -> coalesced wide stores.
  // FULLY UNROLLED over h (compile-time acc indices -- no scratch demotion).
  // Unified tile mapping: wave owns global 16-px tiles g = wpx*PT + i;
  // tile g belongs to half h iff g>>2 == h; row-in-half ii = g&3.
  __syncthreads();  // all K-loop smem reads done before reuse
#pragma unroll
  for (int h = 0; h < 2; ++h) {
    if (GELU) {
      constexpr int STR2 = COUT + 8;     // shorts
      short* t2 = smem;
#pragma unroll
      for (int i = 0; i < PT; ++i) {
        int g = wpx * PT + i;
        if ((g >> 2) == h) {
          int ii = g & 3;
#pragma unroll
          for (int j = 0; j < CT; ++j)
#pragma unroll
            for (int r = 0; r < 4; ++r) {
              int pl = 16 * ii + quad * 4 + r;
              __hip_bfloat16 bv = __float2bfloat16(gelu(acc[i][j][r] + bs[j]));
              t2[pl * STR2 + wc0 + 16 * j + l15] = *(short*)&bv;
            }
        }
      }
      __syncthreads();
      constexpr int CHUNKS = 64 * COUT / 8;   // 1024
      size_t gbase = (((size_t)b * PROWS + m + 1) * PCOLS + 1 + h * 64) * COUT;
      for (int idx = tid; idx < CHUNKS; idx += 256) {
        int px = idx / (COUT / 8), cg = idx % (COUT / 8);
        uint4 v = *(uint4*)&t2[px * STR2 + cg * 8];
        *(uint4*)(hout + gbase + (size_t)px * COUT + cg * 8) = v;
      }
      __syncthreads();
    } else {
      constexpr int STRF = COUT + 4;     // floats
      float* tf = (float*)smem;
#pragma unroll
      for (int i = 0; i < PT; ++i) {
        int g = wpx * PT + i;
        if ((g >> 2) == h) {
          int ii = g & 3;
#pragma unroll
          for (int j = 0; j < CT; ++j)
#pragma unroll
            for (int r = 0; r < 4; ++r) {
              int pl = 16 * ii + quad * 4 + r;
              tf[pl * STRF + wc0 + 16 * j + l15] = acc[i][j][r] + bs[j];
            }
        }
      }
      __syncthreads();
      constexpr int CHUNKS = 64 * COUT / 4;   // 1024
      size_t gbase = (((size_t)b * MMX + m) * NNX + h * 64) * COUT;
      for (int idx = tid; idx < CHUNKS; idx += 256) {
        int px = idx / (COUT / 4), cg = idx % (COUT / 4);
        float4 a4 = *(float4*)&tf[px * STRF + cg * 4];
        size_t gx = gbase + (size_t)px * COUT + cg * 4;
        float4 xv = *(float4*)(xio + gx);
        float4 rr = make_float4(a4.x + xv.x, a4.y + xv.y, a4.z + xv.z, a4.w + xv.w);
        *(float4*)(xio + gx) = rr;
        __hip_bfloat16 o0 = __float2bfloat16(rr.x), o1 = __float2bfloat16(rr.y);
        __hip_bfloat16 o2 = __float2bfloat16(rr.z), o3 = __float2bfloat16(rr.w);
        ushort4 ov = make_ushort4(*(unsigned short*)&o0, *(unsigned short*)&o1,
                                  *(unsigned short*)&o2, *(unsigned short*)&o3);
        *(ushort4*)(xb + gx) = ov;
      }
      __syncthreads();
    }
  }
}

// ---------------------------------------------------------------------------
// head split-K: P[ks][bm][t] = sum_{k in slice} Xb[bm][k] * hwT[t][k]
// grid = Bc * 8; block = 64 bm x 96 t x K=1024. 4 waves = 16 bm each.
// ---------------------------------------------------------------------------
__global__ __launch_bounds__(256) void head_split(
    const __hip_bfloat16* __restrict__ xb,   // [nbm][8192]
    const __hip_bfloat16* __restrict__ hwT,  // [96][8192]
    float* __restrict__ P, int nbm) {        // [8][nbm][96]
  const int ks = blockIdx.x & 7;
  const int bm0 = (blockIdx.x >> 3) * 64;
  const int lane = threadIdx.x & 63;
  const int w = threadIdx.x >> 6;
  const int l15 = lane & 15;
  const int quad = lane >> 4;
  const int bmw = bm0 + w * 16;

  floatx4 acc[6];
#pragma unroll
  for (int j = 0; j < 6; ++j) acc[j] = (floatx4)0.f;

  const int k0 = ks * 1024;
  const __hip_bfloat16* abase = xb + (size_t)(bmw + l15) * 8192 + k0;
  const __hip_bfloat16* bbase = hwT + (size_t)l15 * 8192 + k0;
#pragma unroll 4
  for (int kc = 0; kc < 32; ++kc) {
    const int kb = kc * 32 + quad * 8;
    bfx8 a = *(const bfx8*)(abase + kb);
#pragma unroll
    for (int j = 0; j < 6; ++j) {
      bfx8 bv = *(const bfx8*)(bbase + (size_t)(16 * j) * 8192 + kb);
      acc[j] = __builtin_amdgcn_mfma_f32_16x16x32_bf16(a, bv, acc[j], 0, 0, 0);
    }
  }
#pragma unroll
  for (int j = 0; j < 6; ++j) {
    int t = 16 * j + l15;
#pragma unroll
    for (int r = 0; r < 4; ++r) {
      int bm = bmw + quad * 4 + r;
      P[((size_t)ks * nbm + bm) * TTX + t] = acc[j][r];
    }
  }
}

__global__ __launch_bounds__(256) void head_reduce(
    const float* __restrict__ P, const float* __restrict__ hb,
    float* __restrict__ out, int nbm, int bm_off) {
  int i = blockIdx.x * 256 + threadIdx.x;    // nbm*96
  int t = i % TTX;
  int bm = i / TTX;
  float s = hb[t];
#pragma unroll
  for (int ks = 0; ks < 8; ++ks) s += P[((size_t)ks * nbm + bm) * TTX + t];
  out[(size_t)(bm_off + bm) * TTX + t] = s;
}

// ---------------------------------------------------------------------------
extern "C" void kernel_launch(void* const* d_in, const int* in_sizes, int n_in,
                              void* d_out, int out_size, void* d_ws, size_t ws_size,
                              hipStream_t stream) {
  const float* x      = (const float*)d_in[0];
  const float* emb_w  = (const float*)d_in[1];
  const float* emb_b  = (const float*)d_in[2];
  const float* head_w = (const float*)d_in[3];
  const float* head_b = (const float*)d_in[4];
  const float* dw_w1  = (const float*)d_in[5];
  const float* dw_b1  = (const float*)d_in[6];
  const float* f11_w  = (const float*)d_in[7];
  const float* f11_b  = (const float*)d_in[8];
  const float* f12_w  = (const float*)d_in[9];
  const float* f12_b  = (const float*)d_in[10];
  const float* dw_w2  = (const float*)d_in[11];
  const float* dw_b2  = (const float*)d_in[12];
  const float* f21_w  = (const float*)d_in[13];
  const float* f21_b  = (const float*)d_in[14];
  const float* f22_w  = (const float*)d_in[15];
  const float* f22_b  = (const float*)d_in[16];

  // fixed: 4 conv wT (98304 bf16 each) + hwT (786432 bf16)
  const size_t WEL = 98304, HWEL = 786432;
  __hip_bfloat16* wt11 = (__hip_bfloat16*)d_ws;
  __hip_bfloat16* wt12 = wt11 + WEL;
  __hip_bfloat16* wt21 = wt12 + WEL;
  __hip_bfloat16* wt22 = wt21 + WEL;
  __hip_bfloat16* hwT  = wt22 + WEL;
  char* dyn = (char*)(hwT + HWEL);
  const size_t fixed_bytes = (4 * WEL + HWEL) * 2;

  const size_t YP_B = (size_t)PROWS * PCOLS * DDX * 2;    // 1,114,880
  const size_t HP_B = (size_t)PROWS * PCOLS * RDX * 2;    // 2,229,760
  const size_t X_B  = (size_t)MMX * NNX * DDX * 4;        // 2,097,152
  const size_t XB_B = (size_t)MMX * NNX * DDX * 2;        // 1,048,576
  const size_t P_B  = (size_t)8 * MMX * TTX * 4;          //   196,608
  const size_t PER_B = YP_B + HP_B + X_B + XB_B + P_B;
  int Bc = 32;
  while (Bc > 1 && fixed_bytes + (size_t)Bc * PER_B > ws_size) Bc >>= 1;

  __hip_bfloat16* Yp = (__hip_bfloat16*)dyn;
  __hip_bfloat16* Hp = (__hip_bfloat16*)(dyn + (size_t)Bc * YP_B);
  float* X  = (float*)(dyn + (size_t)Bc * (YP_B + HP_B));
  __hip_bfloat16* Xb = (__hip_bfloat16*)(dyn + (size_t)Bc * (YP_B + HP_B + X_B));
  float* P  = (float*)(dyn + (size_t)Bc * (YP_B + HP_B + X_B + XB_B));
  const int nbm = Bc * MMX;

  // prep (once per launch)
  castw_kernel<<<384, 256, 0, stream>>>(f11_w, wt11, RDX, DDX);
  castw_kernel<<<384, 256, 0, stream>>>(f12_w, wt12, DDX, RDX);
  castw_kernel<<<384, 256, 0, stream>>>(f21_w, wt21, RDX, DDX);
  castw_kernel<<<384, 256, 0, stream>>>(f22_w, wt22, DDX, RDX);
  headw_kernel<<<3072, 256, 0, stream>>>(head_w, hwT);
  // zero padded halo buffers (ws is re-poisoned before every timed launch)
  hipMemsetAsync(Yp, 0, (size_t)Bc * (YP_B + HP_B), stream);

  for (int b0 = 0; b0 < 32; b0 += Bc) {
    int bm_off = b0 * MMX;
    embed_kernel<<<Bc * 2048, 256, 0, stream>>>(x, emb_w, emb_b, X, bm_off);

    for (int l = 0; l < 2; ++l) {
      const float* dwW = l ? dw_w2 : dw_w1;
      const float* dwB = l ? dw_b2 : dw_b1;
      const __hip_bfloat16* w1 = l ? wt21 : wt11;
      const float* b1 = l ? f21_b : f11_b;
      const __hip_bfloat16* w2 = l ? wt22 : wt12;
      const float* b2 = l ? f22_b : f12_b;

      dw_kernel<<<Bc * 32, 256, 0, stream>>>(X, dwW, dwB, Yp);
      conv_lds<DDX, RDX, true, 1>
          <<<Bc * MMX, 256, 0, stream>>>(Yp, w1, b1, Hp, nullptr, nullptr);
      conv_lds<RDX, DDX, false, 2>
          <<<Bc * MMX, 256, 0, stream>>>(Hp, w2, b2, nullptr, X, Xb);
    }

    head_split<<<Bc * 8, 256, 0, stream>>>(Xb, hwT, P, nbm);
    head_reduce<<<Bc * 24, 256, 0, stream>>>(P, head_b, (float*)d_out, nbm, bm_off);
  }
}